// Round 2
// baseline (358.861 us; speedup 1.0000x reference)
//
#include <hip/hip_runtime.h>
#include <hip/hip_bf16.h>

typedef __attribute__((ext_vector_type(8))) short bf16x8;
typedef __attribute__((ext_vector_type(4))) float f32x4;
typedef __attribute__((ext_vector_type(8))) unsigned short u16x8;

#define B_DIM 8192
#define H_DIM 1024
#define K_DIM 2048
#define N_DIM 4096
#define BH (B_DIM * H_DIM)
#define NT 32   // K tiles of 64

__device__ __forceinline__ unsigned short f2bf(float f) {
    union { float f; unsigned u; } v; v.f = f;
    unsigned r = v.u + 0x7FFFu + ((v.u >> 16) & 1u);   // round-to-nearest-even
    return (unsigned short)(r >> 16);
}

__device__ __forceinline__ void gload16(const void* g, void* l) {
    __builtin_amdgcn_global_load_lds(
        (const __attribute__((address_space(1))) void*)g,
        (__attribute__((address_space(3))) void*)l, 16, 0, 0);
}

// ---------------------------------------------------------------------------
// prep_pack: [x|h] fp32 -> bf16 A[8192][2048]. 2048 blocks x 256 thr, 4 chunks
// per thread (grid-stride, consecutive tids -> consecutive 16B stores).
// Split from the old monolithic prep so rocprof exposes its true cost.
// ---------------------------------------------------------------------------
__global__ void prep_pack(const float* __restrict__ x, const float* __restrict__ h,
                          unsigned short* __restrict__ Abf) {
    const int gid0 = blockIdx.x * 256 + threadIdx.x;
#pragma unroll
    for (int it = 0; it < 4; ++it) {
        int gid = gid0 + it * (2048 * 256);
        size_t e = (size_t)gid * 8;
        int m   = gid >> 8;                         // row (2048 elems/row)
        int col = (gid & 255) * 8;
        int p   = col >> 10;                        // 0 = x half, 1 = h half
        int k   = col & 1023;
        const float* src = (p ? h : x) + (size_t)m * 1024 + k;
        float4 v0 = *(const float4*)src;
        float4 v1 = *(const float4*)(src + 4);
        u16x8 o = { f2bf(v0.x), f2bf(v0.y), f2bf(v0.z), f2bf(v0.w),
                    f2bf(v1.x), f2bf(v1.y), f2bf(v1.z), f2bf(v1.w) };
        *(u16x8*)(Abf + e) = o;
    }
}

// ---------------------------------------------------------------------------
// prep_w: W=[Wx;Wh] -> bf16 Bperm (gate-permuted B^T), 64x64 LDS transpose.
//   R = jb*128 + (jj>>4)*64 + gate*16 + (jj&15),  Bperm[R][k] = W[k][n]
// ---------------------------------------------------------------------------
__global__ void prep_w(const float* __restrict__ Wx, const float* __restrict__ Wh,
                       unsigned short* __restrict__ Bperm) {
    __shared__ float tile[64][65];
    const int t  = threadIdx.x;
    const int bz = blockIdx.x;
    const int k0 = (bz & 31) * 64;
    const int n0 = (bz >> 5) * 64;
#pragma unroll
    for (int it = 0; it < 4; ++it) {
        int lin = it * 256 + t;
        int kl  = lin >> 4;
        int n4  = lin & 15;
        int k   = k0 + kl;
        const float* src = (k < 1024) ? (Wx + (size_t)k * 4096 + n0 + n4 * 4)
                                      : (Wh + (size_t)(k - 1024) * 4096 + n0 + n4 * 4);
        float4 v = *(const float4*)src;
        tile[kl][n4 * 4 + 0] = v.x;
        tile[kl][n4 * 4 + 1] = v.y;
        tile[kl][n4 * 4 + 2] = v.z;
        tile[kl][n4 * 4 + 3] = v.w;
    }
    __syncthreads();
#pragma unroll
    for (int it = 0; it < 2; ++it) {
        int lin = it * 256 + t;
        int nl  = lin >> 3;
        int ch  = lin & 7;
        int n    = n0 + nl;
        int gate = n >> 10;
        int j    = n & 1023;
        int jb   = j >> 5;
        int jj   = j & 31;
        int R    = jb * 128 + (jj >> 4) * 64 + gate * 16 + (jj & 15);
        u16x8 o;
#pragma unroll
        for (int q = 0; q < 8; ++q) o[q] = f2bf(tile[ch * 8 + q][nl]);
        *(u16x8*)(Bperm + (size_t)R * 2048 + k0 + ch * 8) = o;
    }
}

// ---------------------------------------------------------------------------
// 256x256 tile, BK=64, 8 waves (2M x 4N), 8-phase schedule, counted vmcnt.
// ROUND-2 FIX vs round 1: every phase now carries the template's pin —
//   BAR(); s_waitcnt lgkmcnt(0) [compiler "memory" fence]; setprio(1);
//   16 MFMA; setprio(0); BAR();
// Without the per-phase fence the compiler reorders ds_read/global_load_lds
// across raw s_barrier (it is NOT a compiler memory fence) and the schedule
// collapses (round-1: MfmaUtil 31%). Also: non-temporal out stores so the
// 96 MB output stream doesn't evict A/B panels from L2/L3 (round-1 FETCH
// 290 MB vs 80 MB ideal).
// Stage slots (one half-tile = 2 gloads/thread per phase), WAR-safe:
//   P1: B0(t+1)  P2: B1(t+1)  P3: A0(t+2)  P4: A1(t+2) [vmcnt(4)]
//   P5: B0(t+2)  P6: B1(t+2)  P7: A0(t+3)  P8: A1(t+3) [vmcnt(4)]
// Gate math: 12 loads outstanding at each gate; oldest 8 (the 4 half-tiles
// the next buffer needs) must land -> s_waitcnt vmcnt(4). Never 0 in loop.
// ---------------------------------------------------------------------------
#define VMW(N)  asm volatile("s_waitcnt vmcnt(" #N ")" ::: "memory")
#define LGKM0() asm volatile("s_waitcnt lgkmcnt(0)" ::: "memory")
#define BAR()   __builtin_amdgcn_s_barrier()

#define LD_A(BUF, TMB) do { \
  _Pragma("unroll") \
  for (int _tm = 0; _tm < 4; ++_tm) \
    _Pragma("unroll") \
    for (int _ks = 0; _ks < 2; ++_ks) \
      af[(TMB) + _tm][_ks] = *(const bf16x8*)(lsA + (BUF) * 16384 + \
          (wm * 128 + ((TMB) + _tm) * 16 + fRow) * 64 + ((_ks * 4 + q4) ^ rx) * 8); \
} while (0)

#define LD_B(BUF, TNB) do { \
  _Pragma("unroll") \
  for (int _tn = 0; _tn < 2; ++_tn) \
    _Pragma("unroll") \
    for (int _ks = 0; _ks < 2; ++_ks) \
      bfr[_tn][_ks] = *(const bf16x8*)(lsB + (BUF) * 16384 + \
          (wn * 64 + ((TNB) + _tn) * 16 + fRow) * 64 + ((_ks * 4 + q4) ^ rx) * 8); \
} while (0)

#define STAGE_A(BUF, H, T) do { \
  gload16(Abf + (size_t)(m0 + (H) * 128 + sRow) * K_DIM + (T) * 64 + sChunk, \
          lsA + (BUF) * 16384 + (H) * 8192 + wave * 512); \
  gload16(Abf + (size_t)(m0 + (H) * 128 + 64 + sRow) * K_DIM + (T) * 64 + sChunk, \
          lsA + (BUF) * 16384 + (H) * 8192 + 4096 + wave * 512); \
} while (0)

#define STAGE_B(BUF, H, T) do { \
  gload16(Bperm + (size_t)(r0 + (H) * 128 + sRow) * K_DIM + (T) * 64 + sChunk, \
          lsB + (BUF) * 16384 + (H) * 8192 + wave * 512); \
  gload16(Bperm + (size_t)(r0 + (H) * 128 + 64 + sRow) * K_DIM + (T) * 64 + sChunk, \
          lsB + (BUF) * 16384 + (H) * 8192 + 4096 + wave * 512); \
} while (0)

// ks outer -> 8 independent MFMAs between dependent pairs on the same acc.
#define MFMA_QUAD(TMB, TNB) do { \
  __builtin_amdgcn_s_setprio(1); \
  _Pragma("unroll") \
  for (int _ks = 0; _ks < 2; ++_ks) \
    _Pragma("unroll") \
    for (int _tm = 0; _tm < 4; ++_tm) \
      _Pragma("unroll") \
      for (int _tn = 0; _tn < 2; ++_tn) \
        acc[(TMB) + _tm][(TNB) + _tn] = __builtin_amdgcn_mfma_f32_16x16x32_bf16( \
            af[(TMB) + _tm][_ks], bfr[_tn][_ks], acc[(TMB) + _tm][(TNB) + _tn], 0, 0, 0); \
  __builtin_amdgcn_s_setprio(0); \
} while (0)

// One pinned phase: reads+stage before the barrier, fenced MFMA after.
#define PHASE(LDS_OPS, STAGE_OP, TMB, TNB) do { \
  LDS_OPS; \
  STAGE_OP; \
  BAR(); \
  LGKM0(); \
  MFMA_QUAD(TMB, TNB); \
  BAR(); \
} while (0)

__global__ __launch_bounds__(512, 2) void lstm_fused(
    const unsigned short* __restrict__ Abf,   // [8192][2048] bf16
    const unsigned short* __restrict__ Bperm, // [4096][2048] bf16 (gate-permuted B^T)
    const float* __restrict__ bx, const float* __restrict__ bh,
    const float* __restrict__ cin, float* __restrict__ out) {
    __shared__ unsigned short lsA[2 * 256 * 64];   // 64 KiB
    __shared__ unsigned short lsB[2 * 256 * 64];   // 64 KiB

    const int tid  = threadIdx.x;
    const int wave = tid >> 6;
    const int lane = tid & 63;
    const int wm   = wave >> 2;                 // 0..1 (M half)
    const int wn   = wave & 3;                  // 0..3 (N quarter)

    // Bijective XCD swizzle: 512 blocks % 8 == 0; each XCD walks M-tiles with
    // a fixed N panel (Bperm panel stays hot in that XCD's L2).
    const int bid = blockIdx.x;
    const int swz = (bid & 7) * 64 + (bid >> 3);
    const int bm  = swz & 31;                   // M tile 0..31
    const int bn  = swz >> 5;                   // N tile 0..15
    const int m0  = bm * 256;
    const int r0  = bn * 256;                   // Bperm row base

    // staging: thread -> (row = it*64 + tid>>3, physical chunk = tid&7)
    // source logical chunk = phys ^ (row&7)  (pre-swizzled global column)
    const int sRow   = tid >> 3;                              // 0..63
    const int sChunk = ((tid & 7) ^ ((tid >> 3) & 7)) * 8;    // element offset

    // fragment read geometry
    const int fRow = lane & 15;
    const int q4   = lane >> 4;                 // 0..3
    const int rx   = fRow & 7;                  // row XOR key

    f32x4 acc[8][4];
#pragma unroll
    for (int i = 0; i < 8; ++i)
#pragma unroll
        for (int j = 0; j < 4; ++j) acc[i][j] = (f32x4){0.f, 0.f, 0.f, 0.f};

    bf16x8 af[8][2];    // all A fragments of current tile (no LDS re-read)
    bf16x8 bfr[2][2];   // current B pair (low or high)

    // ---- prologue: t0 full into buf0, A-halves of t1 into buf1
    STAGE_A(0, 0, 0); STAGE_A(0, 1, 0); STAGE_B(0, 0, 0); STAGE_B(0, 1, 0);
    STAGE_A(1, 0, 1); STAGE_A(1, 1, 1);
    VMW(4);                                      // t0 (8 loads) complete
    BAR();

    // ---- main loop: 15 iterations, tiles 0..29; prefetch t+1..t+3
    for (int i = 0; i < 15; ++i) {
        const int t = 2 * i;
        PHASE(LD_A(0, 0); LD_B(0, 0), STAGE_B(1, 0, t + 1), 0, 0);   // P1
        PHASE(LD_A(0, 4),             STAGE_B(1, 1, t + 1), 4, 0);   // P2
        PHASE(LD_B(0, 2),             STAGE_A(0, 0, t + 2), 4, 2);   // P3
        // P4 (vmcnt gate after MFMA, before the closing barrier)
        STAGE_A(0, 1, t + 2);
        BAR();
        LGKM0();
        MFMA_QUAD(0, 2);
        VMW(4);                                  // t+1 halves complete
        BAR();
        PHASE(LD_A(1, 0); LD_B(1, 0), STAGE_B(0, 0, t + 2), 0, 0);   // P5
        PHASE(LD_A(1, 4),             STAGE_B(0, 1, t + 2), 4, 0);   // P6
        PHASE(LD_B(1, 2),             STAGE_A(1, 0, t + 3), 4, 2);   // P7
        // P8
        STAGE_A(1, 1, t + 3);
        BAR();
        LGKM0();
        MFMA_QUAD(0, 2);
        VMW(4);                                  // t+2 halves complete
        BAR();
    }

    // ---- epilogue: tile 30 (buf0 ready via last loop vmcnt), then tile 31
    STAGE_B(1, 0, 31); STAGE_B(1, 1, 31);        // buf1 B free since P7 of i=14
    LD_A(0, 0); LD_B(0, 0); LGKM0(); MFMA_QUAD(0, 0);
    LD_A(0, 4);             LGKM0(); MFMA_QUAD(4, 0);
    LD_B(0, 2);             LGKM0(); MFMA_QUAD(4, 2); MFMA_QUAD(0, 2);
    VMW(0);                                      // drain A(31)+B(31)
    BAR();
    LD_A(1, 0); LD_B(1, 0); LGKM0(); MFMA_QUAD(0, 0);
    LD_A(1, 4);             LGKM0(); MFMA_QUAD(4, 0);
    LD_B(1, 2);             LGKM0(); MFMA_QUAD(4, 2); MFMA_QUAD(0, 2);

    // ---- LSTM epilogue: tn indexes gate {i,f,g,o}; j fixed per lane.
    const int j = bn * 64 + (wn >> 1) * 32 + (wn & 1) * 16 + fRow;
    const float b_i = bx[j] + bh[j];
    const float b_f = bx[1024 + j] + bh[1024 + j];
    const float b_g = bx[2048 + j] + bh[2048 + j];
    const float b_o = bx[3072 + j] + bh[3072 + j];
#pragma unroll
    for (int tm = 0; tm < 8; ++tm) {
#pragma unroll
        for (int r = 0; r < 4; ++r) {
            const int row = m0 + wm * 128 + tm * 16 + q4 * 4 + r;
            float vi = acc[tm][0][r] + b_i;
            float vf = acc[tm][1][r] + b_f;
            float vg = acc[tm][2][r] + b_g;
            float vo = acc[tm][3][r] + b_o;
            float ig = 1.f / (1.f + __expf(-vi));
            float fg = 1.f / (1.f + __expf(-vf));
            float e2g = __expf(2.f * fminf(fmaxf(vg, -15.f), 15.f));
            float gg = (e2g - 1.f) / (e2g + 1.f);
            float og = 1.f / (1.f + __expf(-vo));
            float cn = fg * cin[(size_t)row * 1024 + j] + ig * gg;
            float e2c = __expf(2.f * fminf(fmaxf(cn, -15.f), 15.f));
            float hn = og * ((e2c - 1.f) / (e2c + 1.f));
            // Non-temporal: out is write-once, keep it from evicting A/B in L2/L3.
            __builtin_nontemporal_store(og, out + (size_t)row * 1024 + j);
            __builtin_nontemporal_store(hn, out + (size_t)BH + (size_t)row * 1024 + j);
            __builtin_nontemporal_store(cn, out + (size_t)2 * BH + (size_t)row * 1024 + j);
        }
    }
}

extern "C" void kernel_launch(void* const* d_in, const int* in_sizes, int n_in,
                              void* d_out, int out_size, void* d_ws, size_t ws_size,
                              hipStream_t stream) {
    const float* x  = (const float*)d_in[0];
    const float* h  = (const float*)d_in[1];
    const float* c  = (const float*)d_in[2];
    const float* Wx = (const float*)d_in[3];
    const float* Wh = (const float*)d_in[4];
    const float* bx = (const float*)d_in[5];
    const float* bh = (const float*)d_in[6];
    float* out = (float*)d_out;

    unsigned short* Abf   = (unsigned short*)d_ws;                                      // 32 MB
    unsigned short* Bperm = (unsigned short*)((char*)d_ws + (size_t)B_DIM * K_DIM * 2); // 16 MB

    hipLaunchKernelGGL(prep_pack, dim3(2048), dim3(256), 0, stream, x, h, Abf);
    hipLaunchKernelGGL(prep_w,    dim3(2048), dim3(256), 0, stream, Wx, Wh, Bperm);
    hipLaunchKernelGGL(lstm_fused, dim3(512), dim3(512), 0, stream,
                       Abf, Bperm, bx, bh, c, out);
}

// Round 4
// 326.671 us; speedup vs baseline: 1.0985x; 1.0985x over previous
//
#include <hip/hip_runtime.h>
#include <hip/hip_bf16.h>

typedef __attribute__((ext_vector_type(8))) short bf16x8;
typedef __attribute__((ext_vector_type(4))) float f32x4;
typedef __attribute__((ext_vector_type(8))) unsigned short u16x8;

#define B_DIM 8192
#define H_DIM 1024
#define K_DIM 2048
#define N_DIM 4096
#define BH (B_DIM * H_DIM)

__device__ __forceinline__ unsigned short f2bf(float f) {
    union { float f; unsigned u; } v; v.f = f;
    unsigned r = v.u + 0x7FFFu + ((v.u >> 16) & 1u);   // round-to-nearest-even
    return (unsigned short)(r >> 16);
}

__device__ __forceinline__ void gload16(const void* g, void* l) {
    __builtin_amdgcn_global_load_lds(
        (const __attribute__((address_space(1))) void*)g,
        (__attribute__((address_space(3))) void*)l, 16, 0, 0);
}

// ---------------------------------------------------------------------------
// prep (merged): blocks [0,2048) pack [x|h] fp32 -> bf16 A[8192][2048]
// (4 x u16x8 chunks per thread, grid-strided, fully coalesced); blocks
// [2048,4096) transpose W=[Wx;Wh] -> bf16 Bperm (gate-permuted B^T) via a
// 64x64 LDS tile. One dispatch so the independent pack and transpose streams
// overlap and one kernel-boundary drain disappears.
// Inputs are read-once -> non-temporal loads via clang ext-vector f32x4
// (__builtin_nontemporal_load rejects HIP_vector_type float4 — round-3 fix).
// Abf/Bperm stores stay cacheable (the GEMM wants them L3-resident).
//   Bperm row map: n = gate*1024 + j; jb=j>>5, jj=j&31 ->
//   R = jb*128 + (jj>>4)*64 + gate*16 + (jj&15),  Bperm[R][k] = W[k][n]
// ---------------------------------------------------------------------------
__global__ void prep(const float* __restrict__ x, const float* __restrict__ h,
                     const float* __restrict__ Wx, const float* __restrict__ Wh,
                     unsigned short* __restrict__ Abf, unsigned short* __restrict__ Bperm) {
    __shared__ float tile[64][65];
    const int t = threadIdx.x;
    if (blockIdx.x < 2048) {
        const int gid0 = blockIdx.x * 256 + t;
#pragma unroll
        for (int it = 0; it < 4; ++it) {
            int gid = gid0 + it * (2048 * 256);
            size_t e = (size_t)gid * 8;
            int m   = gid >> 8;                     // row (2048 elems/row)
            int col = (gid & 255) * 8;
            int p   = col >> 10;                    // 0 = x half, 1 = h half
            int k   = col & 1023;
            const f32x4* src = (const f32x4*)((p ? h : x) + (size_t)m * 1024 + k);
            f32x4 v0 = __builtin_nontemporal_load(src);
            f32x4 v1 = __builtin_nontemporal_load(src + 1);
            u16x8 o = { f2bf(v0.x), f2bf(v0.y), f2bf(v0.z), f2bf(v0.w),
                        f2bf(v1.x), f2bf(v1.y), f2bf(v1.z), f2bf(v1.w) };
            *(u16x8*)(Abf + e) = o;
        }
        return;
    }
    const int bz = blockIdx.x - 2048;
    const int k0 = (bz & 31) * 64;                  // 32 tiles over K
    const int n0 = (bz >> 5) * 64;                  // 64 tiles over N
#pragma unroll
    for (int it = 0; it < 4; ++it) {
        int lin = it * 256 + t;                     // 0..1023 float4 slots
        int kl  = lin >> 4;
        int n4  = lin & 15;
        int k   = k0 + kl;
        const f32x4* src = (const f32x4*)((k < 1024)
                              ? (Wx + (size_t)k * 4096 + n0 + n4 * 4)
                              : (Wh + (size_t)(k - 1024) * 4096 + n0 + n4 * 4));
        f32x4 v = __builtin_nontemporal_load(src);
        tile[kl][n4 * 4 + 0] = v.x;
        tile[kl][n4 * 4 + 1] = v.y;
        tile[kl][n4 * 4 + 2] = v.z;
        tile[kl][n4 * 4 + 3] = v.w;
    }
    __syncthreads();
#pragma unroll
    for (int it = 0; it < 2; ++it) {
        int lin = it * 256 + t;                     // 0..511
        int nl  = lin >> 3;
        int ch  = lin & 7;
        int n    = n0 + nl;
        int gate = n >> 10;
        int j    = n & 1023;
        int jb   = j >> 5;
        int jj   = j & 31;
        int R    = jb * 128 + (jj >> 4) * 64 + gate * 16 + (jj & 15);
        u16x8 o;
#pragma unroll
        for (int q = 0; q < 8; ++q) o[q] = f2bf(tile[ch * 8 + q][nl]);
        *(u16x8*)(Bperm + (size_t)R * 2048 + k0 + ch * 8) = o;
    }
}

// ---------------------------------------------------------------------------
// fused GEMM + LSTM epilogue — VERBATIM round-0 kernel (151.8 µs anchor,
// MfmaUtil 41.5%, 0 bank conflicts, 4 blocks/CU). The 256² 8-phase port
// regressed twice (183, 192 µs); the 4 independent barrier groups per CU
// here absorb the per-K-step vmcnt drain via implicit wave-level overlap.
// 128x128 tile, BK=64, 4 waves, 16x16x32 bf16.
// XOR-swizzled LDS: physical chunk p holds logical (row=p>>3, c=(p&7)^(row&7))
// -> staging source column = ((tid&7) ^ ((tid>>3)&7)) * 8 (dest fixed lane*16),
//    fragment read offset = row*64 + 8*((ks*4 + (lane>>4)) ^ (row&7)).
// ---------------------------------------------------------------------------
__global__ __launch_bounds__(256, 4) void lstm_fused(
    const unsigned short* __restrict__ Abf,   // [8192][2048] bf16
    const unsigned short* __restrict__ Bperm, // [4096][2048] bf16 (permuted B^T)
    const float* __restrict__ bx, const float* __restrict__ bh,
    const float* __restrict__ cin, float* __restrict__ out) {
    __shared__ unsigned short lsA[128 * 64];
    __shared__ unsigned short lsB[128 * 64];

    const int tid  = threadIdx.x;
    const int wave = tid >> 6;
    const int lane = tid & 63;
    const int m0 = blockIdx.x * 128;
    const int jb = blockIdx.y;                  // 0..31
    const int wm = wave >> 1;
    const int wn = wave & 1;

    f32x4 acc[4][4];
#pragma unroll
    for (int i = 0; i < 4; ++i)
#pragma unroll
        for (int j = 0; j < 4; ++j) acc[i][j] = (f32x4){0.f, 0.f, 0.f, 0.f};

    const int sRow   = tid >> 3;                              // 0..31 (+ it*32)
    const int sChunk = (((tid & 7) ^ ((tid >> 3) & 7))) * 8;  // swizzled source col
    const int aBase = (m0 + sRow) * K_DIM + sChunk;
    const int bBase = (jb * 128 + sRow) * K_DIM + sChunk;

    const int fRow  = lane & 15;
    const int qBase = lane >> 4;                // 0..3
    const int rx    = fRow & 7;                 // row XOR key

    for (int kt = 0; kt < 32; ++kt) {
        const int kOff = kt * 64;
#pragma unroll
        for (int it = 0; it < 4; ++it) {
            gload16(Abf + aBase + it * (32 * K_DIM) + kOff, lsA + it * 2048 + wave * 512);
            gload16(Bperm + bBase + it * (32 * K_DIM) + kOff, lsB + it * 2048 + wave * 512);
        }
        __syncthreads();
#pragma unroll
        for (int ks = 0; ks < 2; ++ks) {
            bf16x8 af[4], bfr[4];
            const int qPhys = (ks * 4 + qBase) ^ rx;          // physical chunk
#pragma unroll
            for (int tm = 0; tm < 4; ++tm)
                af[tm] = *(const bf16x8*)(lsA + (wm * 64 + tm * 16 + fRow) * 64 + qPhys * 8);
#pragma unroll
            for (int tn = 0; tn < 4; ++tn)
                bfr[tn] = *(const bf16x8*)(lsB + (wn * 64 + tn * 16 + fRow) * 64 + qPhys * 8);
#pragma unroll
            for (int tm = 0; tm < 4; ++tm)
#pragma unroll
                for (int tn = 0; tn < 4; ++tn)
                    acc[tm][tn] = __builtin_amdgcn_mfma_f32_16x16x32_bf16(
                        af[tm], bfr[tn], acc[tm][tn], 0, 0, 0);
        }
        __syncthreads();
    }

    // Epilogue: tn indexes gate {i,f,g,o}; j fixed per lane.
    const int j = jb * 32 + wn * 16 + fRow;
    const float b_i = bx[j] + bh[j];
    const float b_f = bx[1024 + j] + bh[1024 + j];
    const float b_g = bx[2048 + j] + bh[2048 + j];
    const float b_o = bx[3072 + j] + bh[3072 + j];
#pragma unroll
    for (int tm = 0; tm < 4; ++tm) {
#pragma unroll
        for (int r = 0; r < 4; ++r) {
            const int row = m0 + wm * 64 + tm * 16 + (lane >> 4) * 4 + r;
            float vi = acc[tm][0][r] + b_i;
            float vf = acc[tm][1][r] + b_f;
            float vg = acc[tm][2][r] + b_g;
            float vo = acc[tm][3][r] + b_o;
            float ig = 1.f / (1.f + __expf(-vi));
            float fg = 1.f / (1.f + __expf(-vf));
            float e2g = __expf(2.f * fminf(fmaxf(vg, -15.f), 15.f));
            float gg = (e2g - 1.f) / (e2g + 1.f);
            float og = 1.f / (1.f + __expf(-vo));
            float cn = fg * cin[(size_t)row * 1024 + j] + ig * gg;
            float e2c = __expf(2.f * fminf(fmaxf(cn, -15.f), 15.f));
            float hn = og * ((e2c - 1.f) / (e2c + 1.f));
            out[(size_t)row * 1024 + j] = og;
            out[(size_t)BH + (size_t)row * 1024 + j] = hn;
            out[(size_t)2 * BH + (size_t)row * 1024 + j] = cn;
        }
    }
}

extern "C" void kernel_launch(void* const* d_in, const int* in_sizes, int n_in,
                              void* d_out, int out_size, void* d_ws, size_t ws_size,
                              hipStream_t stream) {
    const float* x  = (const float*)d_in[0];
    const float* h  = (const float*)d_in[1];
    const float* c  = (const float*)d_in[2];
    const float* Wx = (const float*)d_in[3];
    const float* Wh = (const float*)d_in[4];
    const float* bx = (const float*)d_in[5];
    const float* bh = (const float*)d_in[6];
    float* out = (float*)d_out;

    unsigned short* Abf   = (unsigned short*)d_ws;                                      // 32 MB
    unsigned short* Bperm = (unsigned short*)((char*)d_ws + (size_t)B_DIM * K_DIM * 2); // 16 MB

    hipLaunchKernelGGL(prep, dim3(4096), dim3(256), 0, stream, x, h, Wx, Wh, Abf, Bperm);
    hipLaunchKernelGGL(lstm_fused, dim3(B_DIM / 128, 32), dim3(256), 0, stream,
                       Abf, Bperm, bx, bh, c, out);
}